// Round 3
// baseline (1059.733 us; speedup 1.0000x reference)
//
#include <hip/hip_runtime.h>
#include <hip/hip_bf16.h>

// Problem constants
constexpr int kL  = 2048;   // sequence length
constexpr int kD  = 64;     // head dim
constexpr int kBH = 64;     // B*H = 4*16
constexpr size_t kAttnOff = (size_t)kBH * kL * kD * 2;  // output elems before attn

typedef __bf16 bf16x8 __attribute__((ext_vector_type(8)));
typedef __bf16 bf16x4 __attribute__((ext_vector_type(4)));
typedef float  f32x4  __attribute__((ext_vector_type(4)));
typedef unsigned int u32x4 __attribute__((ext_vector_type(4)));

static __device__ inline bf16x8 neg8(bf16x8 v) {
  u32x4 t = __builtin_bit_cast(u32x4, v);
  t ^= 0x80008000u;
  return __builtin_bit_cast(bf16x8, t);
}

// ---------------------------------------------------------------------------
// Fused kernel: e = exp(|<q/8, conj(k)>|); out = (e @ V) / rowsum; e -> ws/attn;
// rowsum -> ws. Flash-style over k-chunks of 64; no max subtraction needed
// (scores >= 0, bounded), so PV accumulates online with no rescaling.
//
// Block: 256 thr / 4 waves; wave owns 32 q-rows (2 tiles of 16); block 128 q.
// LDS: K[64][64]bf16 r/i (8KB each) + V^T[64][64]bf16 r/i (8KB each)
//      + per-wave e-tile [32 q][64 k] bf16 (4KB each). Total 48KB.
// All tiles XOR-swizzled: byte ^= (row&7)<<4  (conflict-free b128 access).
//
// MFMA 16x16x32 bf16 layouts: a[i]=A[lane&15][(lane>>4)*8+i],
//   b[i]=B[(lane>>4)*8+i][lane&15], d[i]=D[(lane>>4)*4+i][lane&15].
// QK swapped: D[k][q] = mfma(K_frag, Q_frag) -> lane(g,r): k=s*16+g*4+i, q=r.
// e round-trips through per-wave LDS to become the PV A-fragment.
// ---------------------------------------------------------------------------
template<int WS>
__global__ __launch_bounds__(256) void fused_kernel(
    const float* __restrict__ qr_g, const float* __restrict__ qi_g,
    const float* __restrict__ kr_g, const float* __restrict__ ki_g,
    const float* __restrict__ vr_g, const float* __restrict__ vi_g,
    __hip_bfloat16* __restrict__ ews, float* __restrict__ attn,
    float* __restrict__ rowsum, float* __restrict__ out)
{
  __shared__ __align__(16) char lds_raw[49152];
  char* kr_l = lds_raw;
  char* ki_l = lds_raw + 8192;
  char* vr_l = lds_raw + 16384;
  char* vi_l = lds_raw + 24576;
  char* e_l  = lds_raw + 32768 + (threadIdx.x >> 6) * 4096;

  const int tid  = threadIdx.x;
  const int wave = tid >> 6;
  const int lane = tid & 63;
  const int g    = lane >> 4;   // 0..3
  const int r    = lane & 15;   // 0..15

  // XCD-bijective swizzle: 1024 blocks = 8 XCDs x 128; 16 consecutive blocks
  // (one bh) land on one XCD -> K/V L2 reuse.
  const int bid = blockIdx.x;
  const int nid = (bid & 7) * 128 + (bid >> 3);
  const int bh  = nid >> 4;
  const int q0w = (nid & 15) * 128 + wave * 32;   // wave's q base (2 tiles)

  // Q fragments, scaled by 1/8 (temperature), bf16.
  bf16x8 aqr[2][2], aqi[2][2];
#pragma unroll
  for (int qt = 0; qt < 2; ++qt) {
    const size_t qbase = ((size_t)bh * kL + q0w + qt * 16 + r) * kD + g * 8;
#pragma unroll
    for (int f = 0; f < 2; ++f) {
      float4 x0 = *(const float4*)(qr_g + qbase + f * 32);
      float4 x1 = *(const float4*)(qr_g + qbase + f * 32 + 4);
      float4 y0 = *(const float4*)(qi_g + qbase + f * 32);
      float4 y1 = *(const float4*)(qi_g + qbase + f * 32 + 4);
      float xr[8] = {x0.x, x0.y, x0.z, x0.w, x1.x, x1.y, x1.z, x1.w};
      float xi[8] = {y0.x, y0.y, y0.z, y0.w, y1.x, y1.y, y1.z, y1.w};
#pragma unroll
      for (int i = 0; i < 8; ++i) {
        aqr[qt][f][i] = (__bf16)(xr[i] * 0.125f);
        aqi[qt][f][i] = (__bf16)(xi[i] * 0.125f);
      }
    }
  }

  float rs[2] = {0.f, 0.f};
  f32x4 o_r[2][4], o_i[2][4];
#pragma unroll
  for (int qt = 0; qt < 2; ++qt)
#pragma unroll
    for (int dt = 0; dt < 4; ++dt) {
      o_r[qt][dt] = (f32x4){0.f, 0.f, 0.f, 0.f};
      o_i[qt][dt] = (f32x4){0.f, 0.f, 0.f, 0.f};
    }

  for (int k0 = 0; k0 < kL; k0 += 64) {
    __syncthreads();
    // ---- Stage K chunk [64 k][64 d] (real+imag), swizzled bf16. ----
    {
      const int row = tid >> 2;
      const int d0  = (tid & 3) << 4;
      const size_t gb = ((size_t)bh * kL + k0 + row) * kD + d0;
      const int base = row * 128 + d0 * 2;
      const int swz  = (row & 7) << 4;
      {
        float4 x0 = *(const float4*)(kr_g + gb);
        float4 x1 = *(const float4*)(kr_g + gb + 4);
        float4 x2 = *(const float4*)(kr_g + gb + 8);
        float4 x3 = *(const float4*)(kr_g + gb + 12);
        bf16x8 p0, p1;
        p0[0]=(__bf16)x0.x; p0[1]=(__bf16)x0.y; p0[2]=(__bf16)x0.z; p0[3]=(__bf16)x0.w;
        p0[4]=(__bf16)x1.x; p0[5]=(__bf16)x1.y; p0[6]=(__bf16)x1.z; p0[7]=(__bf16)x1.w;
        p1[0]=(__bf16)x2.x; p1[1]=(__bf16)x2.y; p1[2]=(__bf16)x2.z; p1[3]=(__bf16)x2.w;
        p1[4]=(__bf16)x3.x; p1[5]=(__bf16)x3.y; p1[6]=(__bf16)x3.z; p1[7]=(__bf16)x3.w;
        *(bf16x8*)(kr_l + (base ^ swz))        = p0;
        *(bf16x8*)(kr_l + ((base + 16) ^ swz)) = p1;
      }
      {
        float4 x0 = *(const float4*)(ki_g + gb);
        float4 x1 = *(const float4*)(ki_g + gb + 4);
        float4 x2 = *(const float4*)(ki_g + gb + 8);
        float4 x3 = *(const float4*)(ki_g + gb + 12);
        bf16x8 p0, p1;
        p0[0]=(__bf16)x0.x; p0[1]=(__bf16)x0.y; p0[2]=(__bf16)x0.z; p0[3]=(__bf16)x0.w;
        p0[4]=(__bf16)x1.x; p0[5]=(__bf16)x1.y; p0[6]=(__bf16)x1.z; p0[7]=(__bf16)x1.w;
        p1[0]=(__bf16)x2.x; p1[1]=(__bf16)x2.y; p1[2]=(__bf16)x2.z; p1[3]=(__bf16)x2.w;
        p1[4]=(__bf16)x3.x; p1[5]=(__bf16)x3.y; p1[6]=(__bf16)x3.z; p1[7]=(__bf16)x3.w;
        *(bf16x8*)(ki_l + (base ^ swz))        = p0;
        *(bf16x8*)(ki_l + ((base + 16) ^ swz)) = p1;
      }
    }
    // ---- Stage V^T chunk: VT[d][k] bf16, swizzled byte ^= (d&7)<<4. ----
    {
      const int p  = tid >> 3;         // k-pair 0..31
      const int d0 = (tid & 7) << 3;   // 0..56
      const size_t gb0 = ((size_t)bh * kL + k0 + 2 * p) * kD + d0;
      const size_t gb1 = gb0 + kD;
      float4 a0 = *(const float4*)(vr_g + gb0);
      float4 a1 = *(const float4*)(vr_g + gb0 + 4);
      float4 a2 = *(const float4*)(vr_g + gb1);
      float4 a3 = *(const float4*)(vr_g + gb1 + 4);
      float4 b0 = *(const float4*)(vi_g + gb0);
      float4 b1 = *(const float4*)(vi_g + gb0 + 4);
      float4 b2 = *(const float4*)(vi_g + gb1);
      float4 b3 = *(const float4*)(vi_g + gb1 + 4);
      float vr0[8] = {a0.x, a0.y, a0.z, a0.w, a1.x, a1.y, a1.z, a1.w};
      float vr1[8] = {a2.x, a2.y, a2.z, a2.w, a3.x, a3.y, a3.z, a3.w};
      float vi0[8] = {b0.x, b0.y, b0.z, b0.w, b1.x, b1.y, b1.z, b1.w};
      float vi1[8] = {b2.x, b2.y, b2.z, b2.w, b3.x, b3.y, b3.z, b3.w};
#pragma unroll
      for (int j = 0; j < 8; ++j) {
        const int d = d0 + j;
        const int byte = (d * 128 + p * 4) ^ ((d & 7) << 4);
        __bf16 pa[2] = {(__bf16)vr0[j], (__bf16)vr1[j]};
        __bf16 pb[2] = {(__bf16)vi0[j], (__bf16)vi1[j]};
        *(unsigned int*)(vr_l + byte) = *(unsigned int*)pa;
        *(unsigned int*)(vi_l + byte) = *(unsigned int*)pb;
      }
    }
    __syncthreads();

    // ---- QK + exp + e to LDS (and global) ----
#pragma unroll
    for (int s = 0; s < 4; ++s) {
      const int krow = s * 16 + r;
      const int swz  = (krow & 7) << 4;
      bf16x8 bkr[2], bki[2], bkin[2];
#pragma unroll
      for (int f = 0; f < 2; ++f) {
        const int byte = (krow * 128 + (f * 32 + g * 8) * 2) ^ swz;
        bkr[f]  = *(const bf16x8*)(kr_l + byte);
        bki[f]  = *(const bf16x8*)(ki_l + byte);
        bkin[f] = neg8(bki[f]);
      }
#pragma unroll
      for (int qt = 0; qt < 2; ++qt) {
        f32x4 accr = {0.f, 0.f, 0.f, 0.f};
        f32x4 acci = {0.f, 0.f, 0.f, 0.f};
#pragma unroll
        for (int f = 0; f < 2; ++f) {
          accr = __builtin_amdgcn_mfma_f32_16x16x32_bf16(bkr[f],  aqr[qt][f], accr, 0, 0, 0);
          accr = __builtin_amdgcn_mfma_f32_16x16x32_bf16(bki[f],  aqi[qt][f], accr, 0, 0, 0);
          acci = __builtin_amdgcn_mfma_f32_16x16x32_bf16(bkr[f],  aqi[qt][f], acci, 0, 0, 0);
          acci = __builtin_amdgcn_mfma_f32_16x16x32_bf16(bkin[f], aqr[qt][f], acci, 0, 0, 0);
        }
        float e[4];
#pragma unroll
        for (int i = 0; i < 4; ++i)
          e[i] = __expf(sqrtf(accr[i] * accr[i] + acci[i] * acci[i]));
        rs[qt] += (e[0] + e[1]) + (e[2] + e[3]);
        bf16x4 pe;
#pragma unroll
        for (int i = 0; i < 4; ++i) pe[i] = (__bf16)e[i];
        // e -> per-wave LDS tile (row = qt*16+r, col = s*16+g*4)
        const int ebyte = ((qt * 16 + r) * 128 + (s * 16 + g * 4) * 2) ^ ((r & 7) << 4);
        *(bf16x4*)(e_l + ebyte) = pe;
        // e -> global (bf16 ws or f32 attn)
        const size_t q = q0w + qt * 16 + r;
        const size_t base = ((size_t)bh * kL + q) * kL + k0 + s * 16 + g * 4;
        if (WS) {
          *(bf16x4*)((__bf16*)ews + base) = pe;
        } else {
          float4 fe = {e[0], e[1], e[2], e[3]};
          *(float4*)(attn + base) = fe;
        }
      }
    }

    // ---- PV: out += e @ V (A-frags re-read from per-wave LDS) ----
#pragma unroll
    for (int c = 0; c < 2; ++c) {
      bf16x8 af[2];
#pragma unroll
      for (int qt = 0; qt < 2; ++qt) {
        const int abyte = ((qt * 16 + r) * 128 + (c * 32 + g * 8) * 2) ^ ((r & 7) << 4);
        af[qt] = *(const bf16x8*)(e_l + abyte);
      }
#pragma unroll
      for (int dt = 0; dt < 4; ++dt) {
        const int d = dt * 16 + r;
        const int byte = (d * 128 + (c * 32 + g * 8) * 2) ^ ((d & 7) << 4);
        bf16x8 bvr = *(const bf16x8*)(vr_l + byte);
        bf16x8 bvi = *(const bf16x8*)(vi_l + byte);
#pragma unroll
        for (int qt = 0; qt < 2; ++qt) {
          o_r[qt][dt] = __builtin_amdgcn_mfma_f32_16x16x32_bf16(af[qt], bvr, o_r[qt][dt], 0, 0, 0);
          o_i[qt][dt] = __builtin_amdgcn_mfma_f32_16x16x32_bf16(af[qt], bvi, o_i[qt][dt], 0, 0, 0);
        }
      }
    }
  }

  // ---- Rowsum reduce (over g groups) + write ----
#pragma unroll
  for (int qt = 0; qt < 2; ++qt) {
    rs[qt] += __shfl_xor(rs[qt], 16, 64);
    rs[qt] += __shfl_xor(rs[qt], 32, 64);
  }
  if (lane < 16) {
#pragma unroll
    for (int qt = 0; qt < 2; ++qt)
      rowsum[(size_t)bh * kL + q0w + qt * 16 + lane] = rs[qt];
  }

  // ---- Epilogue: out = acc / rowsum(row), interleaved (real, imag) ----
#pragma unroll
  for (int qt = 0; qt < 2; ++qt)
#pragma unroll
    for (int i = 0; i < 4; ++i) {
      const float sv = __shfl(rs[qt], g * 4 + i, 64);  // rowsum for row g*4+i
      const float iv = 1.0f / sv;
      const size_t q = q0w + qt * 16 + g * 4 + i;
#pragma unroll
      for (int dt = 0; dt < 4; ++dt) {
        const int d = dt * 16 + r;
        float2 val;
        val.x = o_r[qt][dt][i] * iv;
        val.y = o_i[qt][dt][i] * iv;
        *(float2*)(out + (((size_t)bh * kL + q) * kD + d) * 2) = val;
      }
    }
}

// ---------------------------------------------------------------------------
// Normalize kernel: attn = e * (1/rowsum). Pure streaming.
// Block: 256 thr / 4 waves; each wave handles one q-row (2048 values).
// ---------------------------------------------------------------------------
template<int WS>
__global__ __launch_bounds__(256) void norm_kernel(
    const __hip_bfloat16* __restrict__ ews, float* __restrict__ attn,
    const float* __restrict__ rowsum)
{
  const int wave = threadIdx.x >> 6;
  const int lane = threadIdx.x & 63;
  const int row  = blockIdx.x * 4 + wave;   // bh*2048 + q, flattened
  const float inv = 1.0f / rowsum[row];
  const size_t base = (size_t)row * kL;

  if (WS) {
#pragma unroll
    for (int j = 0; j < 4; ++j) {
      const size_t off = base + j * 512 + lane * 8;
      bf16x8 v = *(const bf16x8*)((const __bf16*)ews + off);
      float4 w0, w1;
      w0.x = (float)v[0] * inv; w0.y = (float)v[1] * inv;
      w0.z = (float)v[2] * inv; w0.w = (float)v[3] * inv;
      w1.x = (float)v[4] * inv; w1.y = (float)v[5] * inv;
      w1.z = (float)v[6] * inv; w1.w = (float)v[7] * inv;
      *(float4*)(attn + off)     = w0;
      *(float4*)(attn + off + 4) = w1;
    }
  } else {
#pragma unroll
    for (int j = 0; j < 4; ++j) {
      const size_t off = base + j * 512 + lane * 8;
      float4 a = *(const float4*)(attn + off);
      float4 b = *(const float4*)(attn + off + 4);
      a.x *= inv; a.y *= inv; a.z *= inv; a.w *= inv;
      b.x *= inv; b.y *= inv; b.z *= inv; b.w *= inv;
      *(float4*)(attn + off)     = a;
      *(float4*)(attn + off + 4) = b;
    }
  }
}

extern "C" void kernel_launch(void* const* d_in, const int* in_sizes, int n_in,
                              void* d_out, int out_size, void* d_ws, size_t ws_size,
                              hipStream_t stream) {
  const float* qr = (const float*)d_in[0];
  const float* qi = (const float*)d_in[1];
  const float* kr = (const float*)d_in[2];
  const float* ki = (const float*)d_in[3];
  const float* vr = (const float*)d_in[4];
  const float* vi = (const float*)d_in[5];
  float* out  = (float*)d_out;
  float* attn = out + kAttnOff;

  float* rowsum = (float*)d_ws;                       // 64*2048 f32 = 512 KB
  const size_t rowsum_bytes = (size_t)kBH * kL * 4;
  __hip_bfloat16* ews = (__hip_bfloat16*)((char*)d_ws + rowsum_bytes);
  const size_t e_bytes = (size_t)kBH * kL * kL * 2;   // 536.9 MB

  const bool use_ws = (ws_size >= rowsum_bytes + e_bytes);

  dim3 gridF(kBH * (kL / 128));        // 1024 blocks, XCD-swizzled inside
  dim3 gridN(kBH * kL / 4);            // 32768 blocks
  if (use_ws) {
    fused_kernel<1><<<gridF, 256, 0, stream>>>(qr, qi, kr, ki, vr, vi, ews, attn, rowsum, out);
    norm_kernel<1><<<gridN, 256, 0, stream>>>(ews, attn, rowsum);
  } else {
    fused_kernel<0><<<gridF, 256, 0, stream>>>(qr, qi, kr, ki, vr, vi, ews, attn, rowsum, out);
    norm_kernel<0><<<gridN, 256, 0, stream>>>(ews, attn, rowsum);
  }
}

// Round 4
// 745.844 us; speedup vs baseline: 1.4209x; 1.4209x over previous
//
#include <hip/hip_runtime.h>
#include <hip/hip_bf16.h>

// Problem constants
constexpr int kL  = 2048;   // sequence length
constexpr int kD  = 64;     // head dim
constexpr int kBH = 64;     // B*H = 4*16
constexpr size_t kAttnOff = (size_t)kBH * kL * kD * 2;  // output elems before attn

typedef __bf16 bf16x8 __attribute__((ext_vector_type(8)));
typedef __bf16 bf16x4 __attribute__((ext_vector_type(4)));
typedef float  f32x4  __attribute__((ext_vector_type(4)));
typedef unsigned int u32x4 __attribute__((ext_vector_type(4)));

static __device__ inline bf16x8 neg8(bf16x8 v) {
  u32x4 t = __builtin_bit_cast(u32x4, v);
  t ^= 0x80008000u;
  return __builtin_bit_cast(bf16x8, t);
}

// ---------------------------------------------------------------------------
// Kernel T: transpose V (f32 [bh][k][d]) -> vt (bf16), tile-blocked and
// PRE-SWIZZLED: tile (bh,kb) = 8KB at ((bh*32+kb)*8192); within the tile,
// element (d, kl) lives at byte (d*128 + (kl*2 ^ ((d&7)<<4))).
// PV kernel then stages tiles with LINEAR coalesced loads + linear LDS writes,
// and its swizzled ds_read_b128 frag reads match this byte order exactly.
// ---------------------------------------------------------------------------
__global__ __launch_bounds__(256) void transpose_v_kernel(
    const float* __restrict__ vr_g, const float* __restrict__ vi_g,
    __hip_bfloat16* __restrict__ vt_r, __hip_bfloat16* __restrict__ vt_i)
{
  __shared__ __align__(16) char lds_raw[2 * 8192];
  char* tr = lds_raw;
  char* ti = lds_raw + 8192;

  const int tid = threadIdx.x;
  const int bh  = blockIdx.x >> 5;
  const int kb  = blockIdx.x & 31;
  const int k0  = kb * 64;

  // Phase 1: stage [64 k][64 d] bf16, swizzled by k-row (conflict-floor).
  {
    const int krow = tid >> 2;
    const int d0   = (tid & 3) << 4;
    const size_t gb = ((size_t)bh * kL + k0 + krow) * kD + d0;
    const int base = krow * 128;
    const int swz  = (krow & 7) << 4;
    {
      float4 x0 = *(const float4*)(vr_g + gb);
      float4 x1 = *(const float4*)(vr_g + gb + 4);
      float4 x2 = *(const float4*)(vr_g + gb + 8);
      float4 x3 = *(const float4*)(vr_g + gb + 12);
      bf16x8 p0, p1;
      p0[0]=(__bf16)x0.x; p0[1]=(__bf16)x0.y; p0[2]=(__bf16)x0.z; p0[3]=(__bf16)x0.w;
      p0[4]=(__bf16)x1.x; p0[5]=(__bf16)x1.y; p0[6]=(__bf16)x1.z; p0[7]=(__bf16)x1.w;
      p1[0]=(__bf16)x2.x; p1[1]=(__bf16)x2.y; p1[2]=(__bf16)x2.z; p1[3]=(__bf16)x2.w;
      p1[4]=(__bf16)x3.x; p1[5]=(__bf16)x3.y; p1[6]=(__bf16)x3.z; p1[7]=(__bf16)x3.w;
      *(bf16x8*)(tr + base + ((d0 * 2) ^ swz))      = p0;
      *(bf16x8*)(tr + base + ((d0 * 2 + 16) ^ swz)) = p1;
    }
    {
      float4 x0 = *(const float4*)(vi_g + gb);
      float4 x1 = *(const float4*)(vi_g + gb + 4);
      float4 x2 = *(const float4*)(vi_g + gb + 8);
      float4 x3 = *(const float4*)(vi_g + gb + 12);
      bf16x8 p0, p1;
      p0[0]=(__bf16)x0.x; p0[1]=(__bf16)x0.y; p0[2]=(__bf16)x0.z; p0[3]=(__bf16)x0.w;
      p0[4]=(__bf16)x1.x; p0[5]=(__bf16)x1.y; p0[6]=(__bf16)x1.z; p0[7]=(__bf16)x1.w;
      p1[0]=(__bf16)x2.x; p1[1]=(__bf16)x2.y; p1[2]=(__bf16)x2.z; p1[3]=(__bf16)x2.w;
      p1[4]=(__bf16)x3.x; p1[5]=(__bf16)x3.y; p1[6]=(__bf16)x3.z; p1[7]=(__bf16)x3.w;
      *(bf16x8*)(ti + base + ((d0 * 2) ^ swz))      = p0;
      *(bf16x8*)(ti + base + ((d0 * 2 + 16) ^ swz)) = p1;
    }
  }
  __syncthreads();

  // Phase 2: gather columns, write vt in the pre-swizzled tile byte order.
  {
    const int d  = tid >> 2;         // 0..63
    const int kc = (tid & 3) << 4;   // 0,16,32,48
    const size_t tb = ((size_t)bh * 32 + kb) * 8192;
    char* outr = (char*)vt_r + tb + d * 128;
    char* outi = (char*)vt_i + tb + d * 128;
    const int oswz = (d & 7) << 4;
    bf16x8 pr0, pr1, pi0, pi1;
#pragma unroll
    for (int j = 0; j < 8; ++j) {
      const int k1 = kc + j;
      const int k2 = kc + 8 + j;
      const int b1 = k1 * 128 + ((d * 2) ^ ((k1 & 7) << 4));
      const int b2 = k2 * 128 + ((d * 2) ^ ((k2 & 7) << 4));
      pr0[j] = *(const __bf16*)(tr + b1);
      pr1[j] = *(const __bf16*)(tr + b2);
      pi0[j] = *(const __bf16*)(ti + b1);
      pi1[j] = *(const __bf16*)(ti + b2);
    }
    *(bf16x8*)(outr + ((kc * 2) ^ oswz))        = pr0;
    *(bf16x8*)(outr + ((kc * 2 + 16) ^ oswz))   = pr1;
    *(bf16x8*)(outi + ((kc * 2) ^ oswz))        = pi0;
    *(bf16x8*)(outi + ((kc * 2 + 16) ^ oswz))   = pi1;
  }
}

// ---------------------------------------------------------------------------
// Kernel A: e = exp(|<q/8, conj(k)>|) -> ews (bf16) or attn (f32); rowsums.
// Block: 256 thr / 4 waves; wave owns 32 q (2 tiles of 16); block 128 q.
// K chunk [64 k][64 d] staged in LDS bf16, XOR-swizzled (conflict-floor).
// Swapped MFMA: D[k][q] = mfma(K_frag, Q_frag).
// e goes acc -> per-wave LDS tile (free 2-way) -> b128 row-gather ->
// 128B-per-row coalesced global stores.
// MFMA 16x16x32 bf16 layouts: a[i]=A[lane&15][(lane>>4)*8+i],
//   b[i]=B[(lane>>4)*8+i][lane&15], d[i]=D[(lane>>4)*4+i][lane&15].
// ---------------------------------------------------------------------------
template<int WS>
__global__ __launch_bounds__(256) void qk_exp_kernel(
    const float* __restrict__ qr_g, const float* __restrict__ qi_g,
    const float* __restrict__ kr_g, const float* __restrict__ ki_g,
    __hip_bfloat16* __restrict__ ews, float* __restrict__ attn,
    float* __restrict__ rowsum)
{
  __shared__ __align__(16) char lds_raw[16384 + 4 * 4096];
  char* kr_l = lds_raw;
  char* ki_l = lds_raw + 8192;
  char* e_l  = lds_raw + 16384 + (threadIdx.x >> 6) * 4096;

  const int tid  = threadIdx.x;
  const int wave = tid >> 6;
  const int lane = tid & 63;
  const int g    = lane >> 4;   // 0..3
  const int r    = lane & 15;   // 0..15

  // XCD-bijective swizzle: 1024 blocks = 8 XCDs x 128; one bh's 16 blocks
  // stay on one XCD -> K reuse in that XCD's L2.
  const int bid = blockIdx.x;
  const int nid = (bid & 7) * 128 + (bid >> 3);
  const int bh  = nid >> 4;
  const int q0w = (nid & 15) * 128 + wave * 32;

  // Q fragments, scaled by 1/8, bf16.
  bf16x8 aqr[2][2], aqi[2][2];
#pragma unroll
  for (int qt = 0; qt < 2; ++qt) {
    const size_t qbase = ((size_t)bh * kL + q0w + qt * 16 + r) * kD + g * 8;
#pragma unroll
    for (int f = 0; f < 2; ++f) {
      float4 x0 = *(const float4*)(qr_g + qbase + f * 32);
      float4 x1 = *(const float4*)(qr_g + qbase + f * 32 + 4);
      float4 y0 = *(const float4*)(qi_g + qbase + f * 32);
      float4 y1 = *(const float4*)(qi_g + qbase + f * 32 + 4);
      float xr[8] = {x0.x, x0.y, x0.z, x0.w, x1.x, x1.y, x1.z, x1.w};
      float xi[8] = {y0.x, y0.y, y0.z, y0.w, y1.x, y1.y, y1.z, y1.w};
#pragma unroll
      for (int i = 0; i < 8; ++i) {
        aqr[qt][f][i] = (__bf16)(xr[i] * 0.125f);
        aqi[qt][f][i] = (__bf16)(xi[i] * 0.125f);
      }
    }
  }

  float rs[2] = {0.f, 0.f};

  for (int k0 = 0; k0 < kL; k0 += 64) {
    __syncthreads();
    // ---- Stage K chunk [64 k][64 d] (real+imag), swizzled bf16. ----
    {
      const int row = tid >> 2;
      const int d0  = (tid & 3) << 4;
      const size_t gb = ((size_t)bh * kL + k0 + row) * kD + d0;
      const int base = row * 128;
      const int swz  = (row & 7) << 4;
      {
        float4 x0 = *(const float4*)(kr_g + gb);
        float4 x1 = *(const float4*)(kr_g + gb + 4);
        float4 x2 = *(const float4*)(kr_g + gb + 8);
        float4 x3 = *(const float4*)(kr_g + gb + 12);
        bf16x8 p0, p1;
        p0[0]=(__bf16)x0.x; p0[1]=(__bf16)x0.y; p0[2]=(__bf16)x0.z; p0[3]=(__bf16)x0.w;
        p0[4]=(__bf16)x1.x; p0[5]=(__bf16)x1.y; p0[6]=(__bf16)x1.z; p0[7]=(__bf16)x1.w;
        p1[0]=(__bf16)x2.x; p1[1]=(__bf16)x2.y; p1[2]=(__bf16)x2.z; p1[3]=(__bf16)x2.w;
        p1[4]=(__bf16)x3.x; p1[5]=(__bf16)x3.y; p1[6]=(__bf16)x3.z; p1[7]=(__bf16)x3.w;
        *(bf16x8*)(kr_l + base + ((d0 * 2) ^ swz))      = p0;
        *(bf16x8*)(kr_l + base + ((d0 * 2 + 16) ^ swz)) = p1;
      }
      {
        float4 x0 = *(const float4*)(ki_g + gb);
        float4 x1 = *(const float4*)(ki_g + gb + 4);
        float4 x2 = *(const float4*)(ki_g + gb + 8);
        float4 x3 = *(const float4*)(ki_g + gb + 12);
        bf16x8 p0, p1;
        p0[0]=(__bf16)x0.x; p0[1]=(__bf16)x0.y; p0[2]=(__bf16)x0.z; p0[3]=(__bf16)x0.w;
        p0[4]=(__bf16)x1.x; p0[5]=(__bf16)x1.y; p0[6]=(__bf16)x1.z; p0[7]=(__bf16)x1.w;
        p1[0]=(__bf16)x2.x; p1[1]=(__bf16)x2.y; p1[2]=(__bf16)x2.z; p1[3]=(__bf16)x2.w;
        p1[4]=(__bf16)x3.x; p1[5]=(__bf16)x3.y; p1[6]=(__bf16)x3.z; p1[7]=(__bf16)x3.w;
        *(bf16x8*)(ki_l + base + ((d0 * 2) ^ swz))      = p0;
        *(bf16x8*)(ki_l + base + ((d0 * 2 + 16) ^ swz)) = p1;
      }
    }
    __syncthreads();

    // ---- QK + exp; e -> per-wave LDS tile [32 q][64 k] ----
#pragma unroll
    for (int s = 0; s < 4; ++s) {
      const int krow = s * 16 + r;
      const int swz  = (krow & 7) << 4;
      bf16x8 bkr[2], bki[2], bkin[2];
#pragma unroll
      for (int f = 0; f < 2; ++f) {
        const int byte = krow * 128 + (((f * 32 + g * 8) * 2) ^ swz);
        bkr[f]  = *(const bf16x8*)(kr_l + byte);
        bki[f]  = *(const bf16x8*)(ki_l + byte);
        bkin[f] = neg8(bki[f]);
      }
#pragma unroll
      for (int qt = 0; qt < 2; ++qt) {
        f32x4 accr = {0.f, 0.f, 0.f, 0.f};
        f32x4 acci = {0.f, 0.f, 0.f, 0.f};
#pragma unroll
        for (int f = 0; f < 2; ++f) {
          accr = __builtin_amdgcn_mfma_f32_16x16x32_bf16(bkr[f],  aqr[qt][f], accr, 0, 0, 0);
          accr = __builtin_amdgcn_mfma_f32_16x16x32_bf16(bki[f],  aqi[qt][f], accr, 0, 0, 0);
          acci = __builtin_amdgcn_mfma_f32_16x16x32_bf16(bkr[f],  aqi[qt][f], acci, 0, 0, 0);
          acci = __builtin_amdgcn_mfma_f32_16x16x32_bf16(bkin[f], aqr[qt][f], acci, 0, 0, 0);
        }
        float e[4];
#pragma unroll
        for (int i = 0; i < 4; ++i)
          e[i] = __expf(sqrtf(accr[i] * accr[i] + acci[i] * acci[i]));
        rs[qt] += (e[0] + e[1]) + (e[2] + e[3]);
        bf16x4 pe;
#pragma unroll
        for (int i = 0; i < 4; ++i) pe[i] = (__bf16)e[i];
        const int row = qt * 16 + r;
        *(bf16x4*)(e_l + row * 128 + (((s * 16 + g * 4) * 2) ^ ((row & 7) << 4))) = pe;
      }
    }

    // ---- Gather e rows -> coalesced global stores (128B per row segment) ----
#pragma unroll
    for (int m = 0; m < 4; ++m) {
      const int row  = m * 8 + (lane >> 3);
      const int byte = row * 128 + (((lane & 7) * 16) ^ ((row & 7) << 4));
      bf16x8 v = *(const bf16x8*)(e_l + byte);
      const size_t base = ((size_t)bh * kL + q0w + row) * kL + k0 + (lane & 7) * 8;
      if (WS) {
        *(bf16x8*)((__bf16*)ews + base) = v;
      } else {
        float4 w0, w1;
        w0.x=(float)v[0]; w0.y=(float)v[1]; w0.z=(float)v[2]; w0.w=(float)v[3];
        w1.x=(float)v[4]; w1.y=(float)v[5]; w1.z=(float)v[6]; w1.w=(float)v[7];
        *(float4*)(attn + base)     = w0;
        *(float4*)(attn + base + 4) = w1;
      }
    }
  }

  // ---- Rowsum reduce (over g groups) + write ----
#pragma unroll
  for (int qt = 0; qt < 2; ++qt) {
    rs[qt] += __shfl_xor(rs[qt], 16, 64);
    rs[qt] += __shfl_xor(rs[qt], 32, 64);
  }
  if (lane < 16) {
#pragma unroll
    for (int qt = 0; qt < 2; ++qt)
      rowsum[(size_t)bh * kL + q0w + qt * 16 + lane] = rs[qt];
  }
}

// ---------------------------------------------------------------------------
// Kernel B: normalized attn (f32) + out = (e @ V) / rowsum (real & imag).
// Block: 256 thr / 4 waves; wave owns 32 q (2 tiles); block 128 q.
// VT=1: V^T tiles pre-transposed/pre-swizzled in ws -> linear coalesced
//       staging (conflict-floor). VT=0: legacy f32 scatter staging.
// ---------------------------------------------------------------------------
template<int WS, int VT>
__global__ __launch_bounds__(256) void pv_kernel(
    const float* __restrict__ vr_g, const float* __restrict__ vi_g,
    const __hip_bfloat16* __restrict__ vt_r, const __hip_bfloat16* __restrict__ vt_i,
    const __hip_bfloat16* __restrict__ ews, float* __restrict__ attn,
    const float* __restrict__ rowsum, float* __restrict__ out)
{
  __shared__ __align__(16) char lds_raw[2 * 8192];
  char* vr_l = lds_raw;
  char* vi_l = lds_raw + 8192;

  const int tid  = threadIdx.x;
  const int wave = tid >> 6;
  const int lane = tid & 63;
  const int g    = lane >> 4;
  const int r    = lane & 15;

  const int bid = blockIdx.x;
  const int nid = (bid & 7) * 128 + (bid >> 3);
  const int bh  = nid >> 4;
  const int q0w = (nid & 15) * 128 + wave * 32;

  float invA[2];
#pragma unroll
  for (int qt = 0; qt < 2; ++qt)
    invA[qt] = 1.0f / rowsum[(size_t)bh * kL + q0w + qt * 16 + r];

  f32x4 o_r[2][4], o_i[2][4];
#pragma unroll
  for (int qt = 0; qt < 2; ++qt)
#pragma unroll
    for (int dt = 0; dt < 4; ++dt) {
      o_r[qt][dt] = (f32x4){0.f, 0.f, 0.f, 0.f};
      o_i[qt][dt] = (f32x4){0.f, 0.f, 0.f, 0.f};
    }

  for (int k0 = 0; k0 < kL; k0 += 64) {
    __syncthreads();
    if (VT) {
      // ---- Linear staging of pre-swizzled V^T tiles (8KB each) ----
      const size_t tb = ((size_t)bh * 32 + (k0 >> 6)) * 8192;
      const int o1 = wave * 1024 + lane * 16;
      const int o2 = o1 + 4096;
      *(u32x4*)(vr_l + o1) = *(const u32x4*)((const char*)vt_r + tb + o1);
      *(u32x4*)(vr_l + o2) = *(const u32x4*)((const char*)vt_r + tb + o2);
      *(u32x4*)(vi_l + o1) = *(const u32x4*)((const char*)vt_i + tb + o1);
      *(u32x4*)(vi_l + o2) = *(const u32x4*)((const char*)vt_i + tb + o2);
    } else {
      // ---- Legacy: f32 V -> transposed scatter (bank-conflicted, fallback) --
      const int p  = tid >> 3;
      const int d0 = (tid & 7) << 3;
      const size_t gb0 = ((size_t)bh * kL + k0 + 2 * p) * kD + d0;
      const size_t gb1 = gb0 + kD;
      float4 a0 = *(const float4*)(vr_g + gb0);
      float4 a1 = *(const float4*)(vr_g + gb0 + 4);
      float4 a2 = *(const float4*)(vr_g + gb1);
      float4 a3 = *(const float4*)(vr_g + gb1 + 4);
      float4 b0 = *(const float4*)(vi_g + gb0);
      float4 b1 = *(const float4*)(vi_g + gb0 + 4);
      float4 b2 = *(const float4*)(vi_g + gb1);
      float4 b3 = *(const float4*)(vi_g + gb1 + 4);
      float vr0[8] = {a0.x, a0.y, a0.z, a0.w, a1.x, a1.y, a1.z, a1.w};
      float vr1[8] = {a2.x, a2.y, a2.z, a2.w, a3.x, a3.y, a3.z, a3.w};
      float vi0[8] = {b0.x, b0.y, b0.z, b0.w, b1.x, b1.y, b1.z, b1.w};
      float vi1[8] = {b2.x, b2.y, b2.z, b2.w, b3.x, b3.y, b3.z, b3.w};
#pragma unroll
      for (int j = 0; j < 8; ++j) {
        const int d = d0 + j;
        const int byte = d * 128 + ((p * 4) ^ ((d & 7) << 4));
        __bf16 pa[2] = {(__bf16)vr0[j], (__bf16)vr1[j]};
        __bf16 pb[2] = {(__bf16)vi0[j], (__bf16)vi1[j]};
        *(unsigned int*)(vr_l + byte) = *(unsigned int*)pa;
        *(unsigned int*)(vi_l + byte) = *(unsigned int*)pb;
      }
    }
    __syncthreads();

#pragma unroll
    for (int kh = 0; kh < 2; ++kh) {
      bf16x8 af[2];
#pragma unroll
      for (int qt = 0; qt < 2; ++qt) {
        const size_t q = q0w + qt * 16 + r;
        const size_t eb = ((size_t)bh * kL + q) * kL + k0 + kh * 32 + g * 8;
        if (WS) {
          af[qt] = *(const bf16x8*)((const __bf16*)ews + eb);
          float4 w0, w1;
          w0.x = (float)af[qt][0] * invA[qt]; w0.y = (float)af[qt][1] * invA[qt];
          w0.z = (float)af[qt][2] * invA[qt]; w0.w = (float)af[qt][3] * invA[qt];
          w1.x = (float)af[qt][4] * invA[qt]; w1.y = (float)af[qt][5] * invA[qt];
          w1.z = (float)af[qt][6] * invA[qt]; w1.w = (float)af[qt][7] * invA[qt];
          *(float4*)(attn + eb)     = w0;
          *(float4*)(attn + eb + 4) = w1;
        } else {
          float4 e0 = *(const float4*)(attn + eb);
          float4 e1 = *(const float4*)(attn + eb + 4);
          af[qt][0]=(__bf16)e0.x; af[qt][1]=(__bf16)e0.y; af[qt][2]=(__bf16)e0.z; af[qt][3]=(__bf16)e0.w;
          af[qt][4]=(__bf16)e1.x; af[qt][5]=(__bf16)e1.y; af[qt][6]=(__bf16)e1.z; af[qt][7]=(__bf16)e1.w;
          float4 w0 = {e0.x * invA[qt], e0.y * invA[qt], e0.z * invA[qt], e0.w * invA[qt]};
          float4 w1 = {e1.x * invA[qt], e1.y * invA[qt], e1.z * invA[qt], e1.w * invA[qt]};
          *(float4*)(attn + eb)     = w0;
          *(float4*)(attn + eb + 4) = w1;
        }
      }
#pragma unroll
      for (int dt = 0; dt < 4; ++dt) {
        const int d = dt * 16 + r;
        const int byte = d * 128 + (((kh * 32 + g * 8) * 2) ^ ((d & 7) << 4));
        bf16x8 bvr = *(const bf16x8*)(vr_l + byte);
        bf16x8 bvi = *(const bf16x8*)(vi_l + byte);
#pragma unroll
        for (int qt = 0; qt < 2; ++qt) {
          o_r[qt][dt] = __builtin_amdgcn_mfma_f32_16x16x32_bf16(af[qt], bvr, o_r[qt][dt], 0, 0, 0);
          o_i[qt][dt] = __builtin_amdgcn_mfma_f32_16x16x32_bf16(af[qt], bvi, o_i[qt][dt], 0, 0, 0);
        }
      }
    }
  }

  // Epilogue: out = acc / rowsum(output row), interleaved (real, imag).
#pragma unroll
  for (int qt = 0; qt < 2; ++qt)
#pragma unroll
    for (int i = 0; i < 4; ++i) {
      const size_t q = q0w + qt * 16 + g * 4 + i;
      const float iv = 1.0f / rowsum[(size_t)bh * kL + q];
#pragma unroll
      for (int dt = 0; dt < 4; ++dt) {
        const int d = dt * 16 + r;
        float2 val;
        val.x = o_r[qt][dt][i] * iv;
        val.y = o_i[qt][dt][i] * iv;
        *(float2*)(out + (((size_t)bh * kL + q) * kD + d) * 2) = val;
      }
    }
}

extern "C" void kernel_launch(void* const* d_in, const int* in_sizes, int n_in,
                              void* d_out, int out_size, void* d_ws, size_t ws_size,
                              hipStream_t stream) {
  const float* qr = (const float*)d_in[0];
  const float* qi = (const float*)d_in[1];
  const float* kr = (const float*)d_in[2];
  const float* ki = (const float*)d_in[3];
  const float* vr = (const float*)d_in[4];
  const float* vi = (const float*)d_in[5];
  float* out  = (float*)d_out;
  float* attn = out + kAttnOff;

  float* rowsum = (float*)d_ws;                        // 512 KB
  const size_t rowsum_bytes = (size_t)kBH * kL * 4;
  __hip_bfloat16* ews = (__hip_bfloat16*)((char*)d_ws + rowsum_bytes);
  const size_t e_bytes = (size_t)kBH * kL * kL * 2;    // 536.9 MB
  const size_t vt_bytes = (size_t)kBH * kD * kL * 2;   // 16.78 MB each
  __hip_bfloat16* vt_r = (__hip_bfloat16*)((char*)d_ws + rowsum_bytes + e_bytes);
  __hip_bfloat16* vt_i = vt_r + (size_t)kBH * kD * kL;

  const bool use_ws = (ws_size >= rowsum_bytes + e_bytes);
  const bool use_vt = (ws_size >= rowsum_bytes + e_bytes + 2 * vt_bytes);

  dim3 gridT(kBH * (kL / 64));    // 2048
  dim3 gridAB(kBH * (kL / 128));  // 1024

  if (use_vt) {
    transpose_v_kernel<<<gridT, 256, 0, stream>>>(vr, vi, vt_r, vt_i);
    qk_exp_kernel<1><<<gridAB, 256, 0, stream>>>(qr, qi, kr, ki, ews, attn, rowsum);
    pv_kernel<1, 1><<<gridAB, 256, 0, stream>>>(vr, vi, vt_r, vt_i, ews, attn, rowsum, out);
  } else if (use_ws) {
    qk_exp_kernel<1><<<gridAB, 256, 0, stream>>>(qr, qi, kr, ki, ews, attn, rowsum);
    pv_kernel<1, 0><<<gridAB, 256, 0, stream>>>(vr, vi, vt_r, vt_i, ews, attn, rowsum, out);
  } else {
    qk_exp_kernel<0><<<gridAB, 256, 0, stream>>>(qr, qi, kr, ki, ews, attn, rowsum);
    pv_kernel<0, 0><<<gridAB, 256, 0, stream>>>(vr, vi, vt_r, vt_i, ews, attn, rowsum, out);
  }
}